// Round 16
// baseline (3880.987 us; speedup 1.0000x reference)
//
#include <hip/hip_runtime.h>
#include <hip/hip_bf16.h>
#include <stdint.h>

typedef __attribute__((ext_vector_type(8))) short bf16x8;
typedef __attribute__((ext_vector_type(4))) float f32x4;
typedef __attribute__((ext_vector_type(8))) unsigned short u16x8;

#define BM 256
#define BN 512
#define BKT 32
#define ALDS (BM * BKT * 2)          // 16384
#define BLDS (BN * BKT * 2)          // 32768
#define BUFB (ALDS + BLDS)           // 49152; 2 buffers = 96 KB LDS

// ---- MXFP8 quant-dequant to bf16 (verified r1/r5-r12: absmax 0.03125) ------
__device__ __forceinline__ float mx_qd_elem(float x, int e) {
    float xs = ldexpf(x, -e);
    xs = fminf(448.f, fmaxf(-448.f, xs));
    float a = fabsf(xs);
    float r;
    if (a < 0.015625f) {                  // below 2^-6: e4m3 subnormal, quantum 2^-9
        r = ldexpf(rintf(ldexpf(a, 9)), -9);
    } else {                              // normal: quantum 2^(E-3)
        int E = (int)((__float_as_uint(a) >> 23) & 0xFF) - 127;
        r = ldexpf(rintf(ldexpf(a, 3 - E)), E - 3);
    }
    r = copysignf(r, xs);
    return ldexpf(r, e);
}

__global__ __launch_bounds__(256) void mx_quant_bf16(
    const float* __restrict__ in, uint16_t* __restrict__ out, int nblk) {
    int t = blockIdx.x * 256 + threadIdx.x;
    if (t >= nblk) return;
    const float4* p = (const float4*)(in + (size_t)t * 32);
    float v[32];
#pragma unroll
    for (int i = 0; i < 8; ++i) {
        float4 fv = p[i];
        v[4 * i + 0] = fv.x; v[4 * i + 1] = fv.y;
        v[4 * i + 2] = fv.z; v[4 * i + 3] = fv.w;
    }
    float amax = 0.f;
#pragma unroll
    for (int i = 0; i < 32; ++i) amax = fmaxf(amax, fabsf(v[i]));
    amax = fmaxf(amax, 1.17549435e-38f);
    int e = (int)((__float_as_uint(amax) >> 23) & 0xFF) - 127 - 8;

    unsigned short res[32];
#pragma unroll
    for (int i = 0; i < 32; ++i) {
        float d = mx_qd_elem(v[i], e);
        res[i] = (unsigned short)(__float_as_uint(d) >> 16);
    }
    u16x8* o = (u16x8*)(out + (size_t)t * 32);
#pragma unroll
    for (int j = 0; j < 4; ++j) {
        u16x8 pack;
#pragma unroll
        for (int i = 0; i < 8; ++i) pack[i] = res[8 * j + i];
        o[j] = pack;
    }
}

// ---- 256x512 big-wave-tile bf16 GEMM: C = A * B^T + bias -------------------
// 8 waves (2M x 4N), per-wave 128x128 (acc[8][8] = 256 regs) -- halves
// frag-read bytes vs 256x256 and cuts staged bytes 25%. launch_bounds(512,1):
// LDS (96 KB) already caps at 1 block/CU, so no reason to cap VGPR at 128
// (the r13/r14/r15 spill cause). BKT=32; r8 counted-lgkm chunk schedule;
// r10 slot-swizzle (quarter-wave: 8 banks x 2 lanes = free, m136);
// XCD map bx=flat&7: each XCD keeps ONE 4 MB B-panel L2-resident all dispatch.
#define GLOAD(srcp, ldsoff)                                                     \
    __builtin_amdgcn_global_load_lds(                                           \
        (const __attribute__((address_space(1))) void*)(srcp),                  \
        (__attribute__((address_space(3))) void*)&lds[ldsoff], 16, 0, 0)

__global__ __launch_bounds__(512, 1) void gemm_bw_bf16(
    const uint16_t* __restrict__ A, const uint16_t* __restrict__ B,
    const float* __restrict__ bias, float* __restrict__ C,
    int Nrows, int K, int O) {
    __shared__ __align__(16) uint8_t lds[2 * BUFB];   // 96 KB

    const int tid  = threadIdx.x;
    const int lane = tid & 63;
    const int w    = tid >> 6;
    const int f    = lane & 15, g = lane >> 4;
    const int wm   = w >> 2,    wn = w & 3;     // 2M x 4N; per-wave 128x128

    // XCD-column map: XCD k (= flat&7, HW round-robin) owns bx=k for the
    // whole dispatch -> its 4 MB B-panel stays L2-resident.
    const int flat = blockIdx.y * gridDim.x + blockIdx.x;   // 0..511
    const int bx   = flat & 7;
    const int by   = flat >> 3;                 // 0..63
    const int rowBase = by * BM, colBase = bx * BN;

    // staging: round = 128 rows x 64 B (8 KB); thread covers 16 B.
    // linear LDS dest (rule 21); SOURCE slot swizzled (r10-verified involution).
    const int srow = tid >> 2;                               // 0..127
    const int ssc  = ((tid & 3) ^ ((srow >> 1) & 3)) * 16;   // source byte col
    const int sld  = tid * 16;
    const size_t K2 = (size_t)K * 2;
    const uint8_t* gAr[2]; const uint8_t* gBr[4];
#pragma unroll
    for (int r = 0; r < 2; ++r)
        gAr[r] = (const uint8_t*)A + (size_t)(rowBase + r * 128 + srow) * K2 + ssc;
#pragma unroll
    for (int r = 0; r < 4; ++r)
        gBr[r] = (const uint8_t*)B + (size_t)(colBase + r * 128 + srow) * K2 + ssc;
#define STAGE(t) do {                                                           \
        const int _buf = ((t) & 1) * BUFB;                                      \
        const size_t _kb = (size_t)(t) * (BKT * 2);                             \
        _Pragma("unroll")                                                       \
        for (int _i = 0; _i < 2; ++_i)                                          \
            GLOAD(gAr[_i] + _kb, _buf + _i * 8192 + sld);                       \
        _Pragma("unroll")                                                       \
        for (int _i = 0; _i < 4; ++_i)                                          \
            GLOAD(gBr[_i] + _kb, _buf + ALDS + _i * 8192 + sld);                \
    } while (0)

    // frag-read offsets: row r (64 B), k-slot g -> r*64 + (g ^ ((r>>1)&3))*16
    int aoff[8], boff[8];
#pragma unroll
    for (int m = 0; m < 8; ++m) {
        int r = wm * 128 + m * 16 + f;
        aoff[m] = r * 64 + ((g ^ ((r >> 1) & 3)) * 16);
    }
#pragma unroll
    for (int n = 0; n < 8; ++n) {
        int r = wn * 128 + n * 16 + f;
        boff[n] = ALDS + r * 64 + ((g ^ ((r >> 1) & 3)) * 16);
    }

    f32x4 acc[8][8];
#pragma unroll
    for (int m = 0; m < 8; ++m)
#pragma unroll
        for (int n = 0; n < 8; ++n)
#pragma unroll
            for (int j = 0; j < 4; ++j) acc[m][n][j] = 0.f;

    const int nt = K / BKT;   // 128

#define WAITL(N) do {                                                           \
        asm volatile("s_waitcnt lgkmcnt(" #N ")" ::: "memory");                 \
        __builtin_amdgcn_sched_barrier(0);                                      \
    } while (0)
// 16-MFMA quadrant: rows MB..MB+3 x cols NB..NB+3
#define MFMA_Q(MB, NB, AF, BF) do {                                             \
        __builtin_amdgcn_s_setprio(1);                                          \
        _Pragma("unroll") for (int _m = 0; _m < 4; ++_m)                        \
        _Pragma("unroll") for (int _n = 0; _n < 4; ++_n)                        \
            acc[(MB) + _m][(NB) + _n] = __builtin_amdgcn_mfma_f32_16x16x32_bf16(\
                AF[_m], BF[_n], acc[(MB) + _m][(NB) + _n], 0, 0, 0);            \
        __builtin_amdgcn_s_setprio(0);                                          \
    } while (0)

    // prologue: stage tile 0, drain, publish
    STAGE(0);
    asm volatile("s_waitcnt vmcnt(0)" ::: "memory");
    __builtin_amdgcn_sched_barrier(0);
    __builtin_amdgcn_s_barrier();
    __builtin_amdgcn_sched_barrier(0);

    for (int t = 0; t < nt; ++t) {
        const int bb = (t & 1) * BUFB;
        const bool pf = (t + 1) < nt;
        bf16x8 aF[4], aG[4], bF[4], bG[4];

        // c0 (8 reads): B n0-3 + A m0-3        [lgkm out: 8]
#pragma unroll
        for (int n = 0; n < 4; ++n) bF[n] = *(const bf16x8*)&lds[bb + boff[n]];
#pragma unroll
        for (int m = 0; m < 4; ++m) aF[m] = *(const bf16x8*)&lds[bb + aoff[m]];
        // c1a (4 reads): A m4-7                [out: 12]
#pragma unroll
        for (int m = 0; m < 4; ++m) aG[m] = *(const bf16x8*)&lds[bb + aoff[4 + m]];
        if (pf) STAGE(t + 1);            // 6 gloads; issue overlaps c0 drain
        WAITL(4);                        // c0 done (c1a outstanding)
        MFMA_Q(0, 0, aF, bF);            // Q1; c1a drains under it
        // c1b (4 reads): B n4-7                [out: 8 -> after Q1 ~4+4]
#pragma unroll
        for (int n = 0; n < 4; ++n) bG[n] = *(const bf16x8*)&lds[bb + boff[4 + n]];
        WAITL(4);                        // c1a done (c1b outstanding)
        MFMA_Q(4, 0, aG, bF);            // Q2; c1b drains under it
        WAITL(0);                        // c1b done
        MFMA_Q(0, 4, aF, bG);            // Q3
        MFMA_Q(4, 4, aG, bG);            // Q4
        // publish tile t+1 (issued ~2400 cyc ago) and release buffers
        asm volatile("s_waitcnt vmcnt(0)" ::: "memory");
        __builtin_amdgcn_sched_barrier(0);
        __builtin_amdgcn_s_barrier();
        __builtin_amdgcn_sched_barrier(0);
    }
#undef STAGE
#undef WAITL
#undef MFMA_Q

    // epilogue: C/D layout col=lane&15, row=(lane>>4)*4+j (r1/r5-r15 verified)
    const int qr = g * 4;
#pragma unroll
    for (int n = 0; n < 8; ++n) {
        int col = colBase + wn * 128 + n * 16 + f;
        float bv = bias[col];
#pragma unroll
        for (int m = 0; m < 8; ++m) {
            int r0 = rowBase + wm * 128 + m * 16 + qr;
#pragma unroll
            for (int j = 0; j < 4; ++j)
                C[(size_t)(r0 + j) * O + col] = acc[m][n][j] + bv;
        }
    }
}

extern "C" void kernel_launch(void* const* d_in, const int* in_sizes, int n_in,
                              void* d_out, int out_size, void* d_ws, size_t ws_size,
                              hipStream_t stream) {
    const float* x    = (const float*)d_in[0];
    const float* wgt  = (const float*)d_in[1];
    const float* bias = (const float*)d_in[2];
    float* out = (float*)d_out;

    const int D_OUT = in_sizes[2];             // 4096
    const int D_IN  = in_sizes[1] / D_OUT;     // 4096
    const int NROWS = in_sizes[0] / D_IN;      // 16384

    uint16_t* xq = (uint16_t*)d_ws;                     // 128 MB
    uint16_t* wq = xq + (size_t)NROWS * D_IN;           //  32 MB

    int nblkx = NROWS * (D_IN / 32);
    int nblkw = D_OUT * (D_IN / 32);
    mx_quant_bf16<<<dim3((nblkx + 255) / 256), dim3(256), 0, stream>>>(x, xq, nblkx);
    mx_quant_bf16<<<dim3((nblkw + 255) / 256), dim3(256), 0, stream>>>(wgt, wq, nblkw);

    dim3 grid(D_OUT / BN, NROWS / BM);   // (8, 64) = 512 blocks
    gemm_bw_bf16<<<grid, dim3(512), 0, stream>>>(xq, wq, bias, out,
                                                 NROWS, D_IN, D_OUT);
}